// Round 1
// baseline (1916.416 us; speedup 1.0000x reference)
//
#include <hip/hip_runtime.h>
#include <math.h>

#define TV 6400
#define NTOT 32

// ============================================================================
// Generic K=64 GEMM: C[n][m, j] = sum_k A[m,k] * B[n][k, j]  (+ bias[m]) (+= )
// Tiles: 64 (m) x 128 (j), micro 4x8, K=64 staged once in LDS.
// ============================================================================
__global__ __launch_bounds__(256) void gemm_k64_kernel(
    const float* __restrict__ A, const float* __restrict__ B,
    float* __restrict__ C, const float* __restrict__ bias,
    int M, long bstride, long cstride, int accum)
{
  __shared__ alignas(16) float Ast[64 * 64];    // [k][m]
  __shared__ alignas(16) float Bs[64 * 128];    // [k][j]
  const int tid = threadIdx.x;
  const int j0 = blockIdx.x * 128;
  const int m0 = blockIdx.y * 64;
  const int n  = blockIdx.z;
  const float* Bn = B + (long)n * bstride;
  float* Cn = C + (long)n * cstride;

  // A: transposed into LDS as [k][m] (A is tiny, L2-resident; write conflict-free)
  for (int idx = tid; idx < 4096; idx += 256) {
    int k = idx >> 6, m = idx & 63;
    Ast[idx] = (m0 + m < M) ? A[(m0 + m) * 64 + k] : 0.f;
  }
  // B: coalesced float4
  for (int idx = tid; idx < 2048; idx += 256) {
    int k = idx >> 5, j4 = idx & 31;
    ((float4*)Bs)[idx] = *(const float4*)(Bn + (long)k * TV + j0 + (j4 << 2));
  }
  __syncthreads();

  const int tx = tid & 15, ty = tid >> 4;
  float acc[4][8] = {};
#pragma unroll 4
  for (int k = 0; k < 64; ++k) {
    const float4 a4 = *(const float4*)&Ast[(k << 6) + (ty << 2)];
    const float4 b0 = *(const float4*)&Bs[(k << 7) + (tx << 3)];
    const float4 b1 = *(const float4*)&Bs[(k << 7) + (tx << 3) + 4];
    const float am[4] = {a4.x, a4.y, a4.z, a4.w};
    const float bj[8] = {b0.x, b0.y, b0.z, b0.w, b1.x, b1.y, b1.z, b1.w};
#pragma unroll
    for (int i = 0; i < 4; ++i)
#pragma unroll
      for (int j = 0; j < 8; ++j) acc[i][j] += am[i] * bj[j];
  }

#pragma unroll
  for (int i = 0; i < 4; ++i) {
    int m = m0 + (ty << 2) + i;
    if (m < M) {
      float bv = bias ? bias[m] : 0.f;
      float* cp = Cn + (long)m * TV + j0 + (tx << 3);
      float4 o0, o1;
      o0.x = acc[i][0] + bv; o0.y = acc[i][1] + bv;
      o0.z = acc[i][2] + bv; o0.w = acc[i][3] + bv;
      o1.x = acc[i][4] + bv; o1.y = acc[i][5] + bv;
      o1.z = acc[i][6] + bv; o1.w = acc[i][7] + bv;
      if (accum) {
        float4 p0 = *(const float4*)cp;
        float4 p1 = *(const float4*)(cp + 4);
        o0.x += p0.x; o0.y += p0.y; o0.z += p0.z; o0.w += p0.w;
        o1.x += p1.x; o1.y += p1.y; o1.z += p1.z; o1.w += p1.w;
      }
      *(float4*)cp = o0;
      *(float4*)(cp + 4) = o1;
    }
  }
}

// ============================================================================
// tcn_w [O=64][C=64][9][1] -> wT [9][c][o] for coalesced staging in tcn kernel
// ============================================================================
__global__ __launch_bounds__(256) void transpose_tcnw(const float* __restrict__ w,
                                                      float* __restrict__ wT)
{
  int idx = blockIdx.x * 256 + threadIdx.x;  // 36864 total
  if (idx < 36864) {
    int kk = idx >> 12;
    int c = (idx >> 6) & 63;
    int o = idx & 63;
    wT[idx] = w[o * 576 + c * 9 + kk];
  }
}

// ============================================================================
// TCN: out[n,o,col] = sum_{c,kk} w[o,c,kk]*gcn[n,c,col+(kk-4)*25] ; epilogue
// +tcn_b -> tBN -> +hidden -> relu -> msg.  9 shifted K=64 GEMM accumulations.
// ============================================================================
__global__ __launch_bounds__(256) void tcn_kernel(
    const float* __restrict__ wT, const float* __restrict__ gcn,
    const float* __restrict__ hid, const float* __restrict__ tcn_b,
    const float* __restrict__ bg, const float* __restrict__ bb,
    const float* __restrict__ bm, const float* __restrict__ bv,
    float* __restrict__ msg)
{
  __shared__ alignas(16) float Ast[64 * 64];    // [c][o]
  __shared__ alignas(16) float Bs[64 * 128];
  const int tid = threadIdx.x;
  const int j0 = blockIdx.x * 128;
  const int n = blockIdx.z;
  const float* gn = gcn + (long)n * 64 * TV;
  const int tx = tid & 15, ty = tid >> 4;
  float acc[4][8] = {};

  for (int kk = 0; kk < 9; ++kk) {
    __syncthreads();
    for (int idx = tid; idx < 1024; idx += 256)
      ((float4*)Ast)[idx] = ((const float4*)wT)[kk * 1024 + idx];
    const int shift = (kk - 4) * 25;
    for (int idx = tid; idx < 8192; idx += 256) {
      int k = idx >> 7, j = idx & 127;
      int col = j0 + j + shift;
      Bs[idx] = (col >= 0 && col < TV) ? gn[(long)k * TV + col] : 0.f;
    }
    __syncthreads();
#pragma unroll 4
    for (int k = 0; k < 64; ++k) {
      const float4 a4 = *(const float4*)&Ast[(k << 6) + (ty << 2)];
      const float4 b0 = *(const float4*)&Bs[(k << 7) + (tx << 3)];
      const float4 b1 = *(const float4*)&Bs[(k << 7) + (tx << 3) + 4];
      const float am[4] = {a4.x, a4.y, a4.z, a4.w};
      const float bj[8] = {b0.x, b0.y, b0.z, b0.w, b1.x, b1.y, b1.z, b1.w};
#pragma unroll
      for (int i = 0; i < 4; ++i)
#pragma unroll
        for (int j = 0; j < 8; ++j) acc[i][j] += am[i] * bj[j];
    }
  }

#pragma unroll
  for (int i = 0; i < 4; ++i) {
    int o = (ty << 2) + i;
    float sc = bg[o] * rsqrtf(bv[o] + 1e-5f);
    float sh = bb[o] - bm[o] * sc;
    float tb = tcn_b[o];
    long base = ((long)n * 64 + o) * TV + j0 + (tx << 3);
    const float* hp = hid + base;
    float* mp = msg + base;
#pragma unroll
    for (int j = 0; j < 8; ++j) {
      float val = (acc[i][j] + tb) * sc + sh + hp[j];
      mp[j] = fmaxf(val, 0.f);
    }
  }
}

// ============================================================================
// Attention: logit[v,w] = scale * sum_{ic,t} a[ic,t,v]*b[ic,t,w]; softmax over
// v (per column w); + (A + PA).  One block per (subset i, n).
// ============================================================================
__global__ __launch_bounds__(256) void att_kernel(
    const float* __restrict__ ab, const float* __restrict__ Amat,
    const float* __restrict__ PAmat, float* __restrict__ att)
{
  const int i = blockIdx.x, n = blockIdx.y;
  const float* arow = ab + (long)n * 96 * TV + (long)(i * 16) * TV;
  const float* brow = arow + (long)48 * TV;
  __shared__ float sA[800], sB[800], sL[625];
  const int tid = threadIdx.x;
  const int a0 = tid >> 4;     // v in {a0, a0+16}
  const int b0 = tid & 15;     // w in {b0, b0+16}
  const int v1 = a0 + 16, w1 = b0 + 16;
  const int v1c = (v1 < 25) ? v1 : 0;
  const int w1c = (w1 < 25) ? w1 : 0;
  float acc00 = 0, acc01 = 0, acc10 = 0, acc11 = 0;

  for (int q = 0; q < 128; ++q) {
    const int ic = q >> 3;
    const int t0 = (q & 7) * 32;  // 32 t rows -> 800 floats
    __syncthreads();
    for (int idx = tid; idx < 800; idx += 256) {
      sA[idx] = arow[(long)ic * TV + t0 * 25 + idx];
      sB[idx] = brow[(long)ic * TV + t0 * 25 + idx];
    }
    __syncthreads();
#pragma unroll
    for (int j = 0; j < 32; ++j) {
      float av0 = sA[j * 25 + a0], av1 = sA[j * 25 + v1c];
      float bv0 = sB[j * 25 + b0], bv1 = sB[j * 25 + w1c];
      acc00 += av0 * bv0; acc01 += av0 * bv1;
      acc10 += av1 * bv0; acc11 += av1 * bv1;
    }
  }

  const float scale = 1.0f / 4096.0f;
  __syncthreads();
  sL[a0 * 25 + b0] = acc00 * scale;
  if (w1 < 25) sL[a0 * 25 + w1] = acc01 * scale;
  if (v1 < 25) sL[v1 * 25 + b0] = acc10 * scale;
  if (v1 < 25 && w1 < 25) sL[v1 * 25 + w1] = acc11 * scale;
  __syncthreads();

  if (tid < 25) {
    const int w = tid;
    float mx = -1e30f;
#pragma unroll
    for (int v = 0; v < 25; ++v) mx = fmaxf(mx, sL[v * 25 + w]);
    float e[25];
    float s = 0.f;
#pragma unroll
    for (int v = 0; v < 25; ++v) { e[v] = __expf(sL[v * 25 + w] - mx); s += e[v]; }
    float inv = 1.f / s;
    float* ap = att + ((long)n * 3 + i) * 625;
#pragma unroll
    for (int v = 0; v < 25; ++v)
      ap[v * 25 + w] = e[v] * inv + Amat[i * 625 + v * 25 + w] + PAmat[i * 625 + v * 25 + w];
  }
}

// ============================================================================
// y[n,o,t,w] = sum_{i,v} u[n,i*64+o,t,v]*att[n,i,v,w] + sum_i cdb[i,o];
// gcn = relu(gBN(y) + hidden).  Block = (o, n); thread = t (256).
// ============================================================================
__global__ __launch_bounds__(256) void att_apply_kernel(
    const float* __restrict__ u, const float* __restrict__ att,
    const float* __restrict__ hid, const float* __restrict__ cdb,
    const float* __restrict__ gg, const float* __restrict__ gb,
    const float* __restrict__ gm, const float* __restrict__ gv,
    float* __restrict__ gcn)
{
  const int o = blockIdx.x, n = blockIdx.y;
  const int tid = threadIdx.x;  // t
  __shared__ alignas(16) float sAtt[3 * 25 * 32];   // rows (i,v), padded to 32
  for (int idx = tid; idx < 2400; idx += 256) sAtt[idx] = 0.f;
  __syncthreads();
  for (int idx = tid; idx < 1875; idx += 256) {
    int i = idx / 625, r = idx % 625;
    sAtt[(i * 25 + r / 25) * 32 + (r % 25)] = att[(long)n * 1875 + idx];
  }
  __syncthreads();

  float4 acc4[7] = {};
  const float* un = u + (long)n * 192 * TV + (long)o * TV + tid * 25;
#pragma unroll
  for (int i = 0; i < 3; ++i) {
    const float* up = un + (long)i * 64 * TV;
#pragma unroll
    for (int v = 0; v < 25; ++v) {
      float uv = up[v];
      const float4* ar = (const float4*)&sAtt[(i * 25 + v) * 32];
#pragma unroll
      for (int j = 0; j < 7; ++j) {
        float4 a = ar[j];
        acc4[j].x += uv * a.x; acc4[j].y += uv * a.y;
        acc4[j].z += uv * a.z; acc4[j].w += uv * a.w;
      }
    }
  }

  const float* accf = (const float*)acc4;
  float bias = cdb[o] + cdb[64 + o] + cdb[128 + o];
  float sc = gg[o] * rsqrtf(gv[o] + 1e-5f);
  float sh = gb[o] - gm[o] * sc;
  long base = ((long)n * 64 + o) * TV + tid * 25;
  const float* hp = hid + base;
  float* gp = gcn + base;
#pragma unroll
  for (int w = 0; w < 25; ++w)
    gp[w] = fmaxf((accf[w] + bias) * sc + sh + hp[w], 0.f);
}

// ============================================================================
// GRU gates (elementwise, float4)
// ============================================================================
__device__ inline float gate1(float rp, float zp, float np, float hv, float hd) {
  float r = 1.f / (1.f + __expf(-rp));
  float z = 1.f / (1.f + __expf(-zp));
  float nn = tanhf(np + r * hv);
  return (1.f - z) * nn + z * hd;
}

__global__ __launch_bounds__(256) void gates_kernel(
    const float* __restrict__ rpre, const float* __restrict__ zpre,
    const float* __restrict__ npre, const float* __restrict__ hh,
    const float* __restrict__ hid, float* __restrict__ out, int n4)
{
  int idx = blockIdx.x * 256 + threadIdx.x;
  if (idx >= n4) return;
  float4 r4 = ((const float4*)rpre)[idx];
  float4 z4 = ((const float4*)zpre)[idx];
  float4 p4 = ((const float4*)npre)[idx];
  float4 h4 = ((const float4*)hh)[idx];
  float4 d4 = ((const float4*)hid)[idx];
  float4 o4;
  o4.x = gate1(r4.x, z4.x, p4.x, h4.x, d4.x);
  o4.y = gate1(r4.y, z4.y, p4.y, h4.y, d4.y);
  o4.z = gate1(r4.z, z4.z, p4.z, h4.z, d4.z);
  o4.w = gate1(r4.w, z4.w, p4.w, h4.w, d4.w);
  ((float4*)out)[idx] = o4;
}

// ============================================================================
extern "C" void kernel_launch(void* const* d_in, const int* in_sizes, int n_in,
                              void* d_out, int out_size, void* d_ws, size_t ws_size,
                              hipStream_t stream)
{
  const float* feature = (const float*)d_in[0];
  const float* hidden  = (const float*)d_in[1];
  const float* Amat    = (const float*)d_in[2];
  const float* PAmat   = (const float*)d_in[3];
  const float* caw = (const float*)d_in[4];
  const float* cab = (const float*)d_in[5];
  const float* cbw = (const float*)d_in[6];
  const float* cbb = (const float*)d_in[7];
  const float* cdw = (const float*)d_in[8];
  const float* cdb = (const float*)d_in[9];
  const float* gbn_g = (const float*)d_in[10];
  const float* gbn_b = (const float*)d_in[11];
  const float* gbn_m = (const float*)d_in[12];
  const float* gbn_v = (const float*)d_in[13];
  const float* tcn_w = (const float*)d_in[14];
  const float* tcn_b = (const float*)d_in[15];
  const float* tbn_g = (const float*)d_in[16];
  const float* tbn_b = (const float*)d_in[17];
  const float* tbn_m = (const float*)d_in[18];
  const float* tbn_v = (const float*)d_in[19];
  const float* W_ir = (const float*)d_in[20];  // dict order: W_ir,W_ii,W_in,W_hr,W_hi,W_hh
  const float* W_ii = (const float*)d_in[21];
  const float* W_in = (const float*)d_in[22];
  const float* W_hr = (const float*)d_in[23];
  const float* W_hi = (const float*)d_in[24];
  const float* W_hh = (const float*)d_in[25];
  const float* b_ir = (const float*)d_in[26];
  const float* b_ii = (const float*)d_in[27];
  const float* b_in = (const float*)d_in[28];
  float* out = (float*)d_out;

  // choose n-chunk so ws fits; layout depends only on ws_size (constant)
  int Nc = NTOT;
  while (Nc > 1 &&
         (((size_t)(96 + 192 + 64 + 64) * TV + 1875) * Nc * 4 + 36864 * 4) > ws_size)
    Nc >>= 1;

  float* ws  = (float*)d_ws;
  float* ab  = ws;                              // [Nc][96][TV]
  float* u   = ab  + (size_t)Nc * 96 * TV;      // [Nc][192][TV]
  float* gcn = u   + (size_t)Nc * 192 * TV;     // [Nc][64][TV]
  float* msg = gcn + (size_t)Nc * 64 * TV;      // [Nc][64][TV]
  float* att = msg + (size_t)Nc * 64 * TV;      // [Nc][3][625]
  float* wT  = att + (size_t)Nc * 1875;         // [9][64][64]
  // GRU buffers alias the (dead by then) ab+u region: 4*64 <= 96+192 rows
  float* rpre = ab;
  float* zpre = rpre + (size_t)Nc * 64 * TV;
  float* npre = zpre + (size_t)Nc * 64 * TV;
  float* hh   = npre + (size_t)Nc * 64 * TV;

  transpose_tcnw<<<dim3(144), dim3(256), 0, stream>>>(tcn_w, wT);

  const long s64 = (long)64 * TV;
  for (int c0 = 0; c0 < NTOT; c0 += Nc) {
    const float* hidc  = hidden  + (long)c0 * s64;
    const float* featc = feature + (long)c0 * s64;
    float* outc = out + (long)c0 * s64;

    // 1. a,b 1x1 convs (rows 0..47 = a, 48..95 = b)
    gemm_k64_kernel<<<dim3(50, 1, Nc), 256, 0, stream>>>(
        caw, hidc, ab, cab, 48, s64, (long)96 * TV, 0);
    gemm_k64_kernel<<<dim3(50, 1, Nc), 256, 0, stream>>>(
        cbw, hidc, ab + (long)48 * TV, cbb, 48, s64, (long)96 * TV, 0);
    // 2. attention matrices
    att_kernel<<<dim3(3, Nc), 256, 0, stream>>>(ab, Amat, PAmat, att);
    // 3. u = cdw @ h (conv_d hoisted before vertex mixing; bias folded later)
    gemm_k64_kernel<<<dim3(50, 3, Nc), 256, 0, stream>>>(
        cdw, hidc, u, nullptr, 192, s64, (long)192 * TV, 0);
    // 4. y = sum_i u_i x att_i ; gcn = relu(gBN(y)+h)
    att_apply_kernel<<<dim3(64, Nc), 256, 0, stream>>>(
        u, att, hidc, cdb, gbn_g, gbn_b, gbn_m, gbn_v, gcn);
    // 5. TCN + tBN + relu(+h) -> msg
    tcn_kernel<<<dim3(50, 1, Nc), 256, 0, stream>>>(
        wT, gcn, hidc, tcn_b, tbn_g, tbn_b, tbn_m, tbn_v, msg);
    // 6. GRU GEMMs
    gemm_k64_kernel<<<dim3(50, 1, Nc), 256, 0, stream>>>(W_ir, featc, rpre, b_ir, 64, s64, s64, 0);
    gemm_k64_kernel<<<dim3(50, 1, Nc), 256, 0, stream>>>(W_hr, msg,   rpre, nullptr, 64, s64, s64, 1);
    gemm_k64_kernel<<<dim3(50, 1, Nc), 256, 0, stream>>>(W_ii, featc, zpre, b_ii, 64, s64, s64, 0);
    gemm_k64_kernel<<<dim3(50, 1, Nc), 256, 0, stream>>>(W_hi, msg,   zpre, nullptr, 64, s64, s64, 1);
    gemm_k64_kernel<<<dim3(50, 1, Nc), 256, 0, stream>>>(W_in, featc, npre, b_in, 64, s64, s64, 0);
    gemm_k64_kernel<<<dim3(50, 1, Nc), 256, 0, stream>>>(W_hh, msg,   hh,   nullptr, 64, s64, s64, 0);
    // 7. gates -> h_new
    int n4 = Nc * 64 * TV / 4;
    gates_kernel<<<dim3((n4 + 255) / 256), 256, 0, stream>>>(
        rpre, zpre, npre, hh, hidc, outc, n4);
  }
}

// Round 2
// 1118.150 us; speedup vs baseline: 1.7139x; 1.7139x over previous
//
#include <hip/hip_runtime.h>
#include <math.h>

#define TV 6400
#define TV4 1600
#define NTOT 32

// ---------------------------------------------------------------------------
// Weight packing: wT (tcn), P_ab (caw|cbw), b_ab, WF (W_ir|W_ii|W_in), bF, WH
// ---------------------------------------------------------------------------
__global__ __launch_bounds__(256) void pack_kernel(
    const float* __restrict__ tcn_w, const float* __restrict__ caw,
    const float* __restrict__ cbw, const float* __restrict__ cab,
    const float* __restrict__ cbb, const float* __restrict__ W_ir,
    const float* __restrict__ W_ii, const float* __restrict__ W_in,
    const float* __restrict__ b_ir, const float* __restrict__ b_ii,
    const float* __restrict__ b_in, const float* __restrict__ W_hr,
    const float* __restrict__ W_hi, const float* __restrict__ W_hh,
    float* __restrict__ P)
{
  int idx = blockIdx.x * 256 + threadIdx.x;
  if (idx < 36864) {                       // wT[kk][c][o]
    int kk = idx >> 12, c = (idx >> 6) & 63, o = idx & 63;
    P[idx] = tcn_w[o * 576 + c * 9 + kk];
  } else if (idx < 43008) {                // P_ab [96][64]
    int r = idx - 36864;
    P[idx] = (r < 3072) ? caw[r] : cbw[r - 3072];
  } else if (idx < 43104) {                // b_ab [96]
    int r = idx - 43008;
    P[idx] = (r < 48) ? cab[r] : cbb[r - 48];
  } else if (idx < 55392) {                // WF [192][64]
    int r = idx - 43104;
    P[idx] = (r < 4096) ? W_ir[r] : (r < 8192 ? W_ii[r - 4096] : W_in[r - 8192]);
  } else if (idx < 55584) {                // bF [192]
    int r = idx - 55392;
    P[idx] = (r < 64) ? b_ir[r] : (r < 128 ? b_ii[r - 64] : b_in[r - 128]);
  } else if (idx < 67872) {                // WH [192][64]
    int r = idx - 55584;
    P[idx] = (r < 4096) ? W_hr[r] : (r < 8192 ? W_hi[r - 4096] : W_hh[r - 8192]);
  }
}

// 32-k microkernel body (macro keeps LDS address space visible to compiler)
#define MICRO_K32(AST, BS)                                                     \
  _Pragma("unroll 8")                                                          \
  for (int k = 0; k < 32; ++k) {                                               \
    float4 aL = *(const float4*)&AST[(k << 6) + (ty << 2)];                    \
    float4 aH = *(const float4*)&AST[(k << 6) + 32 + (ty << 2)];               \
    float4 bL = *(const float4*)&BS[(k << 8) + (tx << 2)];                     \
    float4 bH = *(const float4*)&BS[(k << 8) + 128 + (tx << 2)];               \
    float am[8] = {aL.x, aL.y, aL.z, aL.w, aH.x, aH.y, aH.z, aH.w};            \
    _Pragma("unroll")                                                          \
    for (int r = 0; r < 8; ++r) {                                              \
      accL[r].x += am[r] * bL.x; accL[r].y += am[r] * bL.y;                    \
      accL[r].z += am[r] * bL.z; accL[r].w += am[r] * bL.w;                    \
      accH[r].x += am[r] * bH.x; accH[r].y += am[r] * bH.y;                    \
      accH[r].z += am[r] * bH.z; accH[r].w += am[r] * bH.w;                    \
    }                                                                          \
  }

// ---------------------------------------------------------------------------
// K=64 GEMM, tile 64m x 256j, micro 8x8, K staged in 2 halves (LDS 40 KB)
// C[n][m][j] = sum_k A[m][k] B[n][k][j] + bias[m]
// ---------------------------------------------------------------------------
__global__ __launch_bounds__(256) void gemm_k64_v2(
    const float* __restrict__ A, const float* __restrict__ B,
    float* __restrict__ C, const float* __restrict__ bias,
    int M, long bstride, long cstride)
{
  __shared__ alignas(16) float Ast[32 * 64];
  __shared__ alignas(16) float Bs[32 * 256];
  const int tid = threadIdx.x;
  const int j0 = blockIdx.x * 256;
  const int m0 = blockIdx.y * 64;
  const int n  = blockIdx.z;
  const float* Bn = B + (long)n * bstride;
  float* Cn = C + (long)n * cstride;
  const int tx = tid & 31, ty = tid >> 5;
  float4 accL[8] = {}, accH[8] = {};

  for (int h = 0; h < 2; ++h) {
    __syncthreads();
    for (int idx = tid; idx < 512; idx += 256) {
      int m = idx & 63, k4 = idx >> 6;
      float4 a = (m0 + m < M) ? *(const float4*)(A + (m0 + m) * 64 + h * 32 + k4 * 4)
                              : make_float4(0.f, 0.f, 0.f, 0.f);
      Ast[(k4 * 4 + 0) * 64 + m] = a.x;
      Ast[(k4 * 4 + 1) * 64 + m] = a.y;
      Ast[(k4 * 4 + 2) * 64 + m] = a.z;
      Ast[(k4 * 4 + 3) * 64 + m] = a.w;
    }
    for (int idx = tid; idx < 2048; idx += 256) {
      int k = idx >> 6, j4 = idx & 63;
      ((float4*)Bs)[idx] = *(const float4*)(Bn + (long)(h * 32 + k) * TV + j0 + (j4 << 2));
    }
    __syncthreads();
    MICRO_K32(Ast, Bs)
  }

#pragma unroll
  for (int r = 0; r < 8; ++r) {
    int m = m0 + ((r < 4) ? ((ty << 2) + r) : (32 + (ty << 2) + r - 4));
    if (m < M) {
      float bv = bias ? bias[m] : 0.f;
      float4 oL = accL[r], oH = accH[r];
      oL.x += bv; oL.y += bv; oL.z += bv; oL.w += bv;
      oH.x += bv; oH.y += bv; oH.z += bv; oH.w += bv;
      float* cp = Cn + (long)m * TV + j0 + (tx << 2);
      *(float4*)cp = oL;
      *(float4*)(cp + 128) = oH;
    }
  }
}

// ---------------------------------------------------------------------------
// TCN: 9 column-shifted K=64 GEMM accumulations + tBN + residual relu
// ---------------------------------------------------------------------------
__global__ __launch_bounds__(256) void tcn_v2(
    const float* __restrict__ wT, const float* __restrict__ gcn,
    const float* __restrict__ hid, const float* __restrict__ tcn_b,
    const float* __restrict__ bg, const float* __restrict__ bb,
    const float* __restrict__ bm, const float* __restrict__ bv,
    float* __restrict__ msg)
{
  __shared__ alignas(16) float Ast[32 * 64];
  __shared__ alignas(16) float Bs[32 * 256];
  const int tid = threadIdx.x;
  const int j0 = blockIdx.x * 256;
  const int n = blockIdx.z;
  const float* gn = gcn + (long)n * 64 * TV;
  const int tx = tid & 31, ty = tid >> 5;
  float4 accL[8] = {}, accH[8] = {};

  for (int kk = 0; kk < 9; ++kk) {
    const int shift = (kk - 4) * 25;
    for (int h = 0; h < 2; ++h) {
      __syncthreads();
      for (int idx = tid; idx < 512; idx += 256)
        ((float4*)Ast)[idx] = ((const float4*)wT)[kk * 1024 + h * 512 + idx];
      for (int idx = tid; idx < 8192; idx += 256) {
        int k = idx >> 8, j = idx & 255;
        int col = j0 + j + shift;
        Bs[idx] = (col >= 0 && col < TV) ? gn[(long)(h * 32 + k) * TV + col] : 0.f;
      }
      __syncthreads();
      MICRO_K32(Ast, Bs)
    }
  }

#pragma unroll
  for (int r = 0; r < 8; ++r) {
    int o = (r < 4) ? ((ty << 2) + r) : (32 + (ty << 2) + r - 4);
    float sc = bg[o] * rsqrtf(bv[o] + 1e-5f);
    float sh = bb[o] - bm[o] * sc;
    float tb = tcn_b[o];
    long base = ((long)n * 64 + o) * TV + j0 + (tx << 2);
    float4 hL = *(const float4*)(hid + base);
    float4 hH = *(const float4*)(hid + base + 128);
    float4 oL, oH;
    oL.x = fmaxf((accL[r].x + tb) * sc + sh + hL.x, 0.f);
    oL.y = fmaxf((accL[r].y + tb) * sc + sh + hL.y, 0.f);
    oL.z = fmaxf((accL[r].z + tb) * sc + sh + hL.z, 0.f);
    oL.w = fmaxf((accL[r].w + tb) * sc + sh + hL.w, 0.f);
    oH.x = fmaxf((accH[r].x + tb) * sc + sh + hH.x, 0.f);
    oH.y = fmaxf((accH[r].y + tb) * sc + sh + hH.y, 0.f);
    oH.z = fmaxf((accH[r].z + tb) * sc + sh + hH.z, 0.f);
    oH.w = fmaxf((accH[r].w + tb) * sc + sh + hH.w, 0.f);
    *(float4*)(msg + base) = oL;
    *(float4*)(msg + base + 128) = oH;
  }
}

// ---------------------------------------------------------------------------
// Attention split-K partial: block (chunk, i, n) reduces 256 k-rows -> 25x25
// ---------------------------------------------------------------------------
__global__ __launch_bounds__(256) void att_partial_kernel(
    const float* __restrict__ ab, float* __restrict__ partial)
{
  const int ch = blockIdx.x, i = blockIdx.y, n = blockIdx.z;
  const float* arow = ab + (long)n * 96 * TV + (long)(i * 16) * TV;
  const float* brow = arow + (long)48 * TV;
  const int t0 = ch * 16;
  __shared__ float sA[6400], sB[6400];
  const int tid = threadIdx.x;
  for (int idx = tid; idx < 6400; idx += 256) {
    int ic = idx / 400, rem = idx - ic * 400;
    sA[idx] = arow[(long)ic * TV + t0 * 25 + rem];
    sB[idx] = brow[(long)ic * TV + t0 * 25 + rem];
  }
  __syncthreads();
  const int a0 = tid >> 4, b0 = tid & 15;
  const int v1 = a0 + 16, w1 = b0 + 16;
  const int v1c = (v1 < 25) ? v1 : 0, w1c = (w1 < 25) ? w1 : 0;
  float acc00 = 0, acc01 = 0, acc10 = 0, acc11 = 0;
#pragma unroll 8
  for (int j = 0; j < 256; ++j) {
    float av0 = sA[j * 25 + a0], av1 = sA[j * 25 + v1c];
    float bw0 = sB[j * 25 + b0], bw1 = sB[j * 25 + w1c];
    acc00 += av0 * bw0; acc01 += av0 * bw1;
    acc10 += av1 * bw0; acc11 += av1 * bw1;
  }
  const float scale = 1.0f / 4096.0f;
  float* pp = partial + (((long)(n * 3 + i) * 16) + ch) * 625;
  pp[a0 * 25 + b0] = acc00 * scale;
  if (w1 < 25) pp[a0 * 25 + w1] = acc01 * scale;
  if (v1 < 25) pp[v1 * 25 + b0] = acc10 * scale;
  if (v1 < 25 && w1 < 25) pp[v1 * 25 + w1] = acc11 * scale;
}

// ---------------------------------------------------------------------------
// Reduce partials, column softmax over v, add Aeff
// ---------------------------------------------------------------------------
__global__ __launch_bounds__(256) void att_reduce_kernel(
    const float* __restrict__ partial, const float* __restrict__ Amat,
    const float* __restrict__ PAmat, float* __restrict__ att)
{
  const int i = blockIdx.x, n = blockIdx.y;
  __shared__ float sL[625];
  const int tid = threadIdx.x;
  const float* pp = partial + ((long)(n * 3 + i) * 16) * 625;
  for (int idx = tid; idx < 625; idx += 256) {
    float s = 0.f;
#pragma unroll
    for (int c = 0; c < 16; ++c) s += pp[c * 625 + idx];
    sL[idx] = s;
  }
  __syncthreads();
  if (tid < 25) {
    const int w = tid;
    float mx = -1e30f;
#pragma unroll
    for (int v = 0; v < 25; ++v) mx = fmaxf(mx, sL[v * 25 + w]);
    float e[25];
    float s = 0.f;
#pragma unroll
    for (int v = 0; v < 25; ++v) { e[v] = __expf(sL[v * 25 + w] - mx); s += e[v]; }
    float inv = 1.f / s;
    float* ap = att + ((long)n * 3 + i) * 625;
#pragma unroll
    for (int v = 0; v < 25; ++v)
      ap[v * 25 + w] = e[v] * inv + Amat[i * 625 + v * 25 + w] + PAmat[i * 625 + v * 25 + w];
  }
}

// ---------------------------------------------------------------------------
// y[n,o,t,w] = sum_{i,v} u[n,i*64+o,t,v]*att[n,i,v,w]; gcn = relu(gBN(y)+h)
// ---------------------------------------------------------------------------
__global__ __launch_bounds__(256) void att_apply_kernel(
    const float* __restrict__ u, const float* __restrict__ att,
    const float* __restrict__ hid, const float* __restrict__ cdb,
    const float* __restrict__ gg, const float* __restrict__ gb,
    const float* __restrict__ gm, const float* __restrict__ gv,
    float* __restrict__ gcn)
{
  const int o = blockIdx.x, n = blockIdx.y;
  const int tid = threadIdx.x;  // t
  __shared__ alignas(16) float sAtt[3 * 25 * 32];
  for (int idx = tid; idx < 2400; idx += 256) sAtt[idx] = 0.f;
  __syncthreads();
  for (int idx = tid; idx < 1875; idx += 256) {
    int i = idx / 625, r = idx % 625;
    sAtt[(i * 25 + r / 25) * 32 + (r % 25)] = att[(long)n * 1875 + idx];
  }
  __syncthreads();

  float4 acc4[7] = {};
  const float* un = u + (long)n * 192 * TV + (long)o * TV + tid * 25;
#pragma unroll
  for (int i = 0; i < 3; ++i) {
    const float* up = un + (long)i * 64 * TV;
#pragma unroll
    for (int v = 0; v < 25; ++v) {
      float uv = up[v];
      const float4* ar = (const float4*)&sAtt[(i * 25 + v) * 32];
#pragma unroll
      for (int j = 0; j < 7; ++j) {
        float4 a = ar[j];
        acc4[j].x += uv * a.x; acc4[j].y += uv * a.y;
        acc4[j].z += uv * a.z; acc4[j].w += uv * a.w;
      }
    }
  }

  const float* accf = (const float*)acc4;
  float bias = cdb[o] + cdb[64 + o] + cdb[128 + o];
  float sc = gg[o] * rsqrtf(gv[o] + 1e-5f);
  float sh = gb[o] - gm[o] * sc;
  long base = ((long)n * 64 + o) * TV + tid * 25;
  const float* hp = hid + base;
  float* gp = gcn + base;
#pragma unroll
  for (int w = 0; w < 25; ++w)
    gp[w] = fmaxf((accf[w] + bias) * sc + sh + hp[w], 0.f);
}

// ---------------------------------------------------------------------------
// GRU gates from packed gruF [n][192][TV] (r|z|n) and gruH [n][192][TV]
// ---------------------------------------------------------------------------
__device__ __forceinline__ float gate1(float rp, float zp, float np, float hv, float hd) {
  float r = 1.f / (1.f + __expf(-rp));
  float z = 1.f / (1.f + __expf(-zp));
  float nn = tanhf(np + r * hv);
  return (1.f - z) * nn + z * hd;
}

__global__ __launch_bounds__(256) void gates_kernel(
    const float* __restrict__ gruF, const float* __restrict__ gruH,
    const float* __restrict__ hid, float* __restrict__ out, int total4)
{
  int idx = blockIdx.x * 256 + threadIdx.x;
  if (idx >= total4) return;
  int n = idx / (64 * TV4);
  int rem = idx - n * (64 * TV4);
  long fb = (long)n * 192 * TV4 + rem;
  float4 Fr = ((const float4*)gruF)[fb];
  float4 Fz = ((const float4*)gruF)[fb + (long)64 * TV4];
  float4 Fn = ((const float4*)gruF)[fb + (long)128 * TV4];
  float4 Hr = ((const float4*)gruH)[fb];
  float4 Hz = ((const float4*)gruH)[fb + (long)64 * TV4];
  float4 Hn = ((const float4*)gruH)[fb + (long)128 * TV4];
  float4 hd = ((const float4*)hid)[idx];
  float4 o;
  o.x = gate1(Fr.x + Hr.x, Fz.x + Hz.x, Fn.x, Hn.x, hd.x);
  o.y = gate1(Fr.y + Hr.y, Fz.y + Hz.y, Fn.y, Hn.y, hd.y);
  o.z = gate1(Fr.z + Hr.z, Fz.z + Hz.z, Fn.z, Hn.z, hd.z);
  o.w = gate1(Fr.w + Hr.w, Fz.w + Hz.w, Fn.w, Hn.w, hd.w);
  ((float4*)out)[idx] = o;
}

// ---------------------------------------------------------------------------
extern "C" void kernel_launch(void* const* d_in, const int* in_sizes, int n_in,
                              void* d_out, int out_size, void* d_ws, size_t ws_size,
                              hipStream_t stream)
{
  const float* feature = (const float*)d_in[0];
  const float* hidden  = (const float*)d_in[1];
  const float* Amat    = (const float*)d_in[2];
  const float* PAmat   = (const float*)d_in[3];
  const float* caw = (const float*)d_in[4];
  const float* cab = (const float*)d_in[5];
  const float* cbw = (const float*)d_in[6];
  const float* cbb = (const float*)d_in[7];
  const float* cdw = (const float*)d_in[8];
  const float* cdb = (const float*)d_in[9];
  const float* gbn_g = (const float*)d_in[10];
  const float* gbn_b = (const float*)d_in[11];
  const float* gbn_m = (const float*)d_in[12];
  const float* gbn_v = (const float*)d_in[13];
  const float* tcn_w = (const float*)d_in[14];
  const float* tcn_b = (const float*)d_in[15];
  const float* tbn_g = (const float*)d_in[16];
  const float* tbn_b = (const float*)d_in[17];
  const float* tbn_m = (const float*)d_in[18];
  const float* tbn_v = (const float*)d_in[19];
  const float* W_ir = (const float*)d_in[20];
  const float* W_ii = (const float*)d_in[21];
  const float* W_in = (const float*)d_in[22];
  const float* W_hr = (const float*)d_in[23];
  const float* W_hi = (const float*)d_in[24];
  const float* W_hh = (const float*)d_in[25];
  const float* b_ir = (const float*)d_in[26];
  const float* b_ii = (const float*)d_in[27];
  const float* b_in = (const float*)d_in[28];
  float* out = (float*)d_out;

  // n-chunk sizing (layout depends only on ws_size; identical every call)
  int Nc = NTOT;
  while (Nc > 1) {
    size_t attsz = ((size_t)Nc * 1875 + 3) & ~(size_t)3;
    size_t need = ((size_t)512 * TV * Nc + (size_t)Nc * 30000 + attsz + 67872) * 4;
    if (need <= ws_size) break;
    Nc >>= 1;
  }
  size_t attsz = ((size_t)Nc * 1875 + 3) & ~(size_t)3;

  float* ws = (float*)d_ws;
  float* R1 = ws;                              // [Nc][192][TV]: ab (96 rows) then gruH
  float* R2 = R1 + (size_t)192 * TV * Nc;      // [Nc][192][TV]: u then gruF
  float* R3 = R2 + (size_t)192 * TV * Nc;      // [Nc][64][TV]: gcn
  float* R4 = R3 + (size_t)64 * TV * Nc;       // [Nc][64][TV]: msg
  float* partial = R4 + (size_t)64 * TV * Nc;  // [Nc][3][16][625]
  float* att = partial + (size_t)Nc * 30000;   // [Nc][3][625]
  float* P = att + attsz;                      // packed weights
  float* wT  = P;
  float* Pab = P + 36864;
  float* bab = P + 43008;
  float* WF  = P + 43104;
  float* bF  = P + 55392;
  float* WH  = P + 55584;

  pack_kernel<<<dim3(266), dim3(256), 0, stream>>>(
      tcn_w, caw, cbw, cab, cbb, W_ir, W_ii, W_in, b_ir, b_ii, b_in,
      W_hr, W_hi, W_hh, P);

  const long s64 = (long)64 * TV;
  for (int c0 = 0; c0 < NTOT; c0 += Nc) {
    const float* hidc  = hidden  + (long)c0 * s64;
    const float* featc = feature + (long)c0 * s64;
    float* outc = out + (long)c0 * s64;

    // 1. a|b 1x1 convs, packed M=96 -> ab = R1 as [Nc][96][TV]
    gemm_k64_v2<<<dim3(25, 2, Nc), 256, 0, stream>>>(
        Pab, hidc, R1, bab, 96, s64, (long)96 * TV);
    // 2. attention: split-K partials + reduce/softmax
    att_partial_kernel<<<dim3(16, 3, Nc), 256, 0, stream>>>(R1, partial);
    att_reduce_kernel<<<dim3(3, Nc), 256, 0, stream>>>(partial, Amat, PAmat, att);
    // 3. u = cdw @ h (M=192)
    gemm_k64_v2<<<dim3(25, 3, Nc), 256, 0, stream>>>(
        cdw, hidc, R2, nullptr, 192, s64, (long)192 * TV);
    // 4. vertex mixing + gBN + relu + residual -> gcn
    att_apply_kernel<<<dim3(64, Nc), 256, 0, stream>>>(
        R2, att, hidc, cdb, gbn_g, gbn_b, gbn_m, gbn_v, R3);
    // 5. TCN + tBN + relu(+h) -> msg
    tcn_v2<<<dim3(25, 1, Nc), 256, 0, stream>>>(
        wT, R3, hidc, tcn_b, tbn_g, tbn_b, tbn_m, tbn_v, R4);
    // 6. GRU GEMMs, packed M=192 (u dead -> R2; ab dead -> R1)
    gemm_k64_v2<<<dim3(25, 3, Nc), 256, 0, stream>>>(
        WF, featc, R2, bF, 192, s64, (long)192 * TV);
    gemm_k64_v2<<<dim3(25, 3, Nc), 256, 0, stream>>>(
        WH, R4, R1, nullptr, 192, s64, (long)192 * TV);
    // 7. gates -> h_new
    int total4 = Nc * 64 * TV4;
    gates_kernel<<<dim3((total4 + 255) / 256), 256, 0, stream>>>(
        R2, R1, hidc, outc, total4);
  }
}

// Round 3
// 456.559 us; speedup vs baseline: 4.1975x; 2.4491x over previous
//
#include <hip/hip_runtime.h>
#include <math.h>

#define TV 6400
#define NTOT 32

typedef __attribute__((ext_vector_type(8))) short short8;
typedef __attribute__((ext_vector_type(4))) short short4v;
typedef __attribute__((ext_vector_type(4))) float f32x4;

__device__ __forceinline__ float b2f(short s) {
  unsigned u = ((unsigned)(unsigned short)s) << 16;
  return __uint_as_float(u);
}
__device__ __forceinline__ short f2b(float f) {
  unsigned u = __float_as_uint(f);
  u = (u + 0x7FFF + ((u >> 16) & 1)) >> 16;
  return (short)u;
}

// ===========================================================================
// Pack weights to bf16 frag-major (unit = 64 lanes x 8 bf16 = one a-frag).
// Layout (short8 units): Wab[0,768) Wu[768,2304) WF[2304,3840) WH[3840,5376)
// wT[5376,9984).  Biases fp32 in Pb: bab[0,96) bF[96,288).
// ===========================================================================
__global__ __launch_bounds__(256) void pack_kernel(
    const float* __restrict__ tcn_w, const float* __restrict__ caw,
    const float* __restrict__ cbw, const float* __restrict__ cdw,
    const float* __restrict__ W_ir, const float* __restrict__ W_ii,
    const float* __restrict__ W_in, const float* __restrict__ W_hr,
    const float* __restrict__ W_hi, const float* __restrict__ W_hh,
    const float* __restrict__ cab, const float* __restrict__ cbb,
    const float* __restrict__ b_ir, const float* __restrict__ b_ii,
    const float* __restrict__ b_in,
    short* __restrict__ P, float* __restrict__ Pb)
{
  int idx = blockIdx.x * 256 + threadIdx.x;
  if (idx < 9984) {
    int lane = idx & 63;
    int rest = idx >> 6;
    int c = rest & 1;
    rest >>= 1;  // 0..77: mf-group id
    int mloc = lane & 15, kb = c * 32 + (lane >> 4) * 8;
    short8 v;
    if (rest < 6) {            // Wab: caw|cbw rows [96][64]
      int m = rest * 16 + mloc;
      for (int i = 0; i < 8; ++i)
        v[i] = f2b(m < 48 ? caw[m * 64 + kb + i] : cbw[(m - 48) * 64 + kb + i]);
    } else if (rest < 18) {    // Wu: cdw [192][64]
      int m = (rest - 6) * 16 + mloc;
      for (int i = 0; i < 8; ++i) v[i] = f2b(cdw[m * 64 + kb + i]);
    } else if (rest < 30) {    // WF: W_ir|W_ii|W_in [192][64]
      int m = (rest - 18) * 16 + mloc;
      const float* W = (m < 64) ? W_ir : (m < 128 ? W_ii : W_in);
      int mr = m & 63;
      for (int i = 0; i < 8; ++i) v[i] = f2b(W[mr * 64 + kb + i]);
    } else if (rest < 42) {    // WH: W_hr|W_hi|W_hh
      int m = (rest - 30) * 16 + mloc;
      const float* W = (m < 64) ? W_hr : (m < 128 ? W_hi : W_hh);
      int mr = m & 63;
      for (int i = 0; i < 8; ++i) v[i] = f2b(W[mr * 64 + kb + i]);
    } else {                   // wT: tcn_w [o][cch][kk], unit (kk*4+mf)
      int t = rest - 42;       // 0..35
      int kk = t >> 2, mf = t & 3;
      int o = mf * 16 + mloc;
      for (int i = 0; i < 8; ++i) v[i] = f2b(tcn_w[o * 576 + (kb + i) * 9 + kk]);
    }
    *(short8*)(P + (size_t)idx * 8) = v;
  } else if (idx < 9984 + 288) {
    int r = idx - 9984;
    if (r < 96) Pb[r] = (r < 48) ? cab[r] : cbb[r - 48];
    else {
      int q = r - 96;
      Pb[r] = (q < 64) ? b_ir[q] : (q < 128 ? b_ii[q - 64] : b_in[q - 128]);
    }
  }
}

// ===========================================================================
// fp32 [64][TV] -> KJ8 bf16 [8][TV][8] for hidden and feature
// ===========================================================================
__global__ __launch_bounds__(256) void convert_kernel(
    const float* __restrict__ hid, const float* __restrict__ feat,
    short* __restrict__ hidK, short* __restrict__ featK)
{
  int j = blockIdx.x * 256 + threadIdx.x;  // 0..6399
  int gy = blockIdx.y;                     // which*8+g
  int n = blockIdx.z;
  const float* src = ((gy < 8) ? hid : feat) + ((long)n * 64 + (long)(gy & 7) * 8) * TV + j;
  short* dst = ((gy < 8) ? hidK : featK) + (((long)n * 8 + (gy & 7)) * TV + j) * 8;
  short8 o;
#pragma unroll
  for (int i = 0; i < 8; ++i) o[i] = f2b(src[(long)i * TV]);
  *(short8*)dst = o;
}

// ===========================================================================
// Generic MFMA GEMM: C[m][j] = sum_k W[m][k] B[k][j] (+bias), K=64.
// W frag-major, B in KJ8. Block tile 64m x 128j, 4 waves (2 j-frags each).
// out_kj8: 1 -> KJ8 bf16 output (direct short4 stores); 0 -> row-major bf16.
// ===========================================================================
__global__ __launch_bounds__(256) void gemm_mfma(
    const short8* __restrict__ Wp, const short8* __restrict__ Bk,
    short* __restrict__ Cout, const float* __restrict__ bias,
    int M, int out_kj8, long b_n_units, long c_n_shorts)
{
  __shared__ short sO[64 * 136];
  const int tid = threadIdx.x;
  const int lane = tid & 63, w = tid >> 6;
  const int q = lane >> 4, lj = lane & 15;
  const int j0 = blockIdx.x * 128;
  const int m0 = blockIdx.y * 64;
  const int n = blockIdx.z;
  const short8* Bn = Bk + (long)n * b_n_units;
  short* Cn = Cout + (long)n * c_n_shorts;
  int nmf = (M - m0 + 15) >> 4; if (nmf > 4) nmf = 4;

  f32x4 acc[4][2];
  for (int a = 0; a < 4; ++a) for (int b = 0; b < 2; ++b)
    acc[a][b] = (f32x4){0.f, 0.f, 0.f, 0.f};

  for (int c = 0; c < 2; ++c) {
    short8 bf0 = Bn[(long)(c * 4 + q) * TV + j0 + (w * 2 + 0) * 16 + lj];
    short8 bf1 = Bn[(long)(c * 4 + q) * TV + j0 + (w * 2 + 1) * 16 + lj];
#pragma unroll
    for (int mf = 0; mf < 4; ++mf) {
      if (mf < nmf) {
        short8 af = Wp[(((m0 >> 4) + mf) * 2 + c) * 64 + lane];
        acc[mf][0] = __builtin_amdgcn_mfma_f32_16x16x32_bf16(af, bf0, acc[mf][0], 0, 0, 0);
        acc[mf][1] = __builtin_amdgcn_mfma_f32_16x16x32_bf16(af, bf1, acc[mf][1], 0, 0, 0);
      }
    }
  }

  if (out_kj8) {
    for (int mf = 0; mf < nmf; ++mf) {
      int k0 = m0 + mf * 16 + q * 4;
      int g = k0 >> 3, i0 = k0 & 7;
      float bv[4];
#pragma unroll
      for (int r = 0; r < 4; ++r) bv[r] = bias ? bias[k0 + r] : 0.f;
#pragma unroll
      for (int jf = 0; jf < 2; ++jf) {
        int j = j0 + (w * 2 + jf) * 16 + lj;
        short4v o4;
#pragma unroll
        for (int r = 0; r < 4; ++r) o4[r] = f2b(acc[mf][jf][r] + bv[r]);
        *(short4v*)(Cn + ((long)g * TV + j) * 8 + i0) = o4;
      }
    }
  } else {
    for (int mf = 0; mf < nmf; ++mf) {
      int r0 = mf * 16 + q * 4;
      float bv[4];
#pragma unroll
      for (int r = 0; r < 4; ++r) bv[r] = bias ? bias[m0 + r0 + r] : 0.f;
#pragma unroll
      for (int jf = 0; jf < 2; ++jf) {
        int cl = (w * 2 + jf) * 16 + lj;
#pragma unroll
        for (int r = 0; r < 4; ++r)
          sO[(r0 + r) * 136 + cl] = f2b(acc[mf][jf][r] + bv[r]);
      }
    }
    __syncthreads();
    int rows = nmf * 16;
    for (int u = tid; u < rows * 16; u += 256) {
      int row = u >> 4, cu = u & 15;
      short8 vv = *(const short8*)&sO[row * 136 + cu * 8];
      *(short8*)(Cn + (long)(m0 + row) * TV + j0 + cu * 8) = vv;
    }
  }
}

// ===========================================================================
// TCN via MFMA: out[o][j] = sum_kk sum_c wT[kk][o][c] gcn[c][j+(kk-4)*25]
// B from gcnK (KJ8): shifts are address offsets, OOB lanes zeroed.
// Epilogue: (acc+tcn_b)*bn + hid, relu -> msgK (KJ8).
// ===========================================================================
__global__ __launch_bounds__(256) void tcn_mfma(
    const short8* __restrict__ wTp, const short8* __restrict__ gcnK,
    const short* __restrict__ hidK, const float* __restrict__ tcn_b,
    const float* __restrict__ pbg, const float* __restrict__ pbb,
    const float* __restrict__ pbm, const float* __restrict__ pbv,
    short* __restrict__ msgK)
{
  __shared__ float A2[64], B2[64];
  const int tid = threadIdx.x;
  if (tid < 64) {
    float sc = pbg[tid] * rsqrtf(pbv[tid] + 1e-5f);
    A2[tid] = sc;
    B2[tid] = tcn_b[tid] * sc + (pbb[tid] - pbm[tid] * sc);
  }
  __syncthreads();
  const int lane = tid & 63, w = tid >> 6;
  const int q = lane >> 4, lj = lane & 15;
  const int j0 = blockIdx.x * 128;
  const int n = blockIdx.y;
  const short8* Bn = gcnK + (long)n * 8 * TV;
  const short8 zero8 = {0, 0, 0, 0, 0, 0, 0, 0};

  f32x4 acc[4][2];
  for (int a = 0; a < 4; ++a) for (int b = 0; b < 2; ++b)
    acc[a][b] = (f32x4){0.f, 0.f, 0.f, 0.f};

  for (int kk = 0; kk < 9; ++kk) {
    const int shift = (kk - 4) * 25;
    for (int c = 0; c < 2; ++c) {
      short8 bfv[2];
#pragma unroll
      for (int jf = 0; jf < 2; ++jf) {
        int col = j0 + (w * 2 + jf) * 16 + lj + shift;
        bool valid = ((unsigned)col < (unsigned)TV);
        short8 t = Bn[(long)(c * 4 + q) * TV + (valid ? col : 0)];
        bfv[jf] = valid ? t : zero8;
      }
#pragma unroll
      for (int mf = 0; mf < 4; ++mf) {
        short8 af = wTp[((kk * 4 + mf) * 2 + c) * 64 + lane];
        acc[mf][0] = __builtin_amdgcn_mfma_f32_16x16x32_bf16(af, bfv[0], acc[mf][0], 0, 0, 0);
        acc[mf][1] = __builtin_amdgcn_mfma_f32_16x16x32_bf16(af, bfv[1], acc[mf][1], 0, 0, 0);
      }
    }
  }

  short* Mn = msgK + (long)n * 64 * TV;
  const short* Hn = hidK + (long)n * 64 * TV;
#pragma unroll
  for (int mf = 0; mf < 4; ++mf) {
    int k0 = mf * 16 + q * 4;
    int g = k0 >> 3, i0 = k0 & 7;
#pragma unroll
    for (int jf = 0; jf < 2; ++jf) {
      int j = j0 + (w * 2 + jf) * 16 + lj;
      long base = ((long)g * TV + j) * 8 + i0;
      short4v h4 = *(const short4v*)&Hn[base];
      short4v o4;
#pragma unroll
      for (int r = 0; r < 4; ++r) {
        float v = acc[mf][jf][r] * A2[k0 + r] + B2[k0 + r] + b2f(h4[r]);
        o4[r] = f2b(fmaxf(v, 0.f));
      }
      *(short4v*)&Mn[base] = o4;
    }
  }
}

// ===========================================================================
// Attention split-K partial from abK (KJ8 bf16): 16 t-rows -> 25x25 partial
// ===========================================================================
__global__ __launch_bounds__(256) void att_partial(
    const short* __restrict__ abK, float* __restrict__ partial)
{
  const int ch = blockIdx.x, i = blockIdx.y, n = blockIdx.z;
  __shared__ float sA[6400], sB[6400];
  const int tid = threadIdx.x;
  const long nb = (long)n * 96 * TV;
  const int t0 = ch * 16;
  for (int idx = tid; idx < 800; idx += 256) {
    int gh = idx / 400, jl = idx - gh * 400;
    long j = (long)t0 * 25 + jl;
    short8 va = *(const short8*)&abK[nb + ((long)(2 * i + gh) * TV + j) * 8];
    short8 vb = *(const short8*)&abK[nb + ((long)(6 + 2 * i + gh) * TV + j) * 8];
#pragma unroll
    for (int e = 0; e < 8; ++e) {
      sA[(gh * 8 + e) * 400 + jl] = b2f(va[e]);
      sB[(gh * 8 + e) * 400 + jl] = b2f(vb[e]);
    }
  }
  __syncthreads();
  const int a0 = tid >> 4, b0 = tid & 15;
  const int v1 = a0 + 16, w1 = b0 + 16;
  const int v1c = (v1 < 25) ? v1 : 0, w1c = (w1 < 25) ? w1 : 0;
  float acc00 = 0, acc01 = 0, acc10 = 0, acc11 = 0;
#pragma unroll 8
  for (int r = 0; r < 256; ++r) {
    float av0 = sA[r * 25 + a0], av1 = sA[r * 25 + v1c];
    float bw0 = sB[r * 25 + b0], bw1 = sB[r * 25 + w1c];
    acc00 += av0 * bw0; acc01 += av0 * bw1;
    acc10 += av1 * bw0; acc11 += av1 * bw1;
  }
  const float scale = 1.0f / 4096.0f;
  float* pp = partial + (((long)(n * 3 + i) * 16) + ch) * 625;
  pp[a0 * 25 + b0] = acc00 * scale;
  if (w1 < 25) pp[a0 * 25 + w1] = acc01 * scale;
  if (v1 < 25) pp[v1 * 25 + b0] = acc10 * scale;
  if (v1 < 25 && w1 < 25) pp[v1 * 25 + w1] = acc11 * scale;
}

// ===========================================================================
// Reduce partials, column softmax over v, add A+PA
// ===========================================================================
__global__ __launch_bounds__(256) void att_reduce(
    const float* __restrict__ partial, const float* __restrict__ Amat,
    const float* __restrict__ PAmat, float* __restrict__ att)
{
  const int i = blockIdx.x, n = blockIdx.y;
  __shared__ float sL[625];
  const int tid = threadIdx.x;
  const float* pp = partial + ((long)(n * 3 + i) * 16) * 625;
  for (int idx = tid; idx < 625; idx += 256) {
    float s = 0.f;
#pragma unroll
    for (int c = 0; c < 16; ++c) s += pp[c * 625 + idx];
    sL[idx] = s;
  }
  __syncthreads();
  if (tid < 25) {
    const int w = tid;
    float mx = -1e30f;
#pragma unroll
    for (int v = 0; v < 25; ++v) mx = fmaxf(mx, sL[v * 25 + w]);
    float e[25];
    float s = 0.f;
#pragma unroll
    for (int v = 0; v < 25; ++v) { e[v] = __expf(sL[v * 25 + w] - mx); s += e[v]; }
    float inv = 1.f / s;
    float* ap = att + ((long)n * 3 + i) * 625;
#pragma unroll
    for (int v = 0; v < 25; ++v)
      ap[v * 25 + w] = e[v] * inv + Amat[i * 625 + v * 25 + w] + PAmat[i * 625 + v * 25 + w];
  }
}

// ===========================================================================
// Vertex mixing: gcn = relu(gBN(sum_i u_i x att_i + bias) + hid) -> gcnK(KJ8)
// Block (og of 8 o's, tc of 32 t's, n); threads = 32t x 8o.
// ===========================================================================
__global__ __launch_bounds__(256) void att_apply(
    const short* __restrict__ u, const float* __restrict__ att,
    const short* __restrict__ hidK, const float* __restrict__ cdb,
    const float* __restrict__ gg, const float* __restrict__ gb,
    const float* __restrict__ gm, const float* __restrict__ gv,
    short* __restrict__ gcnK)
{
  const int og = blockIdx.x, tc = blockIdx.y, n = blockIdx.z;
  __shared__ short sU[24 * 800];
  __shared__ float sAtt[75 * 28];
  __shared__ short sOut[8 * 800];
  const int tid = threadIdx.x;
  const long ubase = (long)n * 192 * TV;
  const int jb = tc * 800;
  for (int idx = tid; idx < 2400; idx += 256) {
    int row = idx / 100, cu = idx - row * 100;
    int i = row >> 3, oo = row & 7;
    *(short8*)&sU[row * 800 + cu * 8] =
        *(const short8*)&u[ubase + (long)(i * 64 + og * 8 + oo) * TV + jb + cu * 8];
  }
  for (int idx = tid; idx < 1875; idx += 256) {
    int i = idx / 625, r = idx - i * 625;
    sAtt[(i * 25 + r / 25) * 28 + (r % 25)] = att[(long)n * 1875 + idx];
  }
  __syncthreads();
  const int oo = tid >> 5, tl = tid & 31;
  const int o = og * 8 + oo;
  float acc[25];
#pragma unroll
  for (int w2 = 0; w2 < 25; ++w2) acc[w2] = 0.f;
#pragma unroll
  for (int i = 0; i < 3; ++i) {
    const short* up = &sU[(i * 8 + oo) * 800 + tl * 25];
    const float* ar = &sAtt[i * 25 * 28];
#pragma unroll
    for (int v = 0; v < 25; ++v) {
      float uv = b2f(up[v]);
      const float* aw = ar + v * 28;
#pragma unroll
      for (int w2 = 0; w2 < 25; ++w2) acc[w2] += uv * aw[w2];
    }
  }
  float bias = cdb[o] + cdb[64 + o] + cdb[128 + o];
  float sc = gg[o] * rsqrtf(gv[o] + 1e-5f);
  float sh = gb[o] - gm[o] * sc;
  const long hbase = (((long)n * 8 + og) * TV) * 8 + oo;
#pragma unroll
  for (int w2 = 0; w2 < 25; ++w2) {
    float h = b2f(hidK[hbase + (long)(jb + tl * 25 + w2) * 8]);
    float val = fmaxf((acc[w2] + bias) * sc + sh + h, 0.f);
    sOut[oo * 800 + tl * 25 + w2] = f2b(val);
  }
  __syncthreads();
  for (int jl = tid; jl < 800; jl += 256) {
    short8 ov;
#pragma unroll
    for (int e = 0; e < 8; ++e) ov[e] = sOut[e * 800 + jl];
    *(short8*)&gcnK[(((long)n * 8 + og) * TV + jb + jl) * 8] = ov;
  }
}

// ===========================================================================
// Fused GRU: F = WF@featK, H = WH@msgK (M=192 each), gates, out fp32.
// Block tile 64j; weights staged in LDS (frag-major); epilogue aliases LDS.
// ===========================================================================
__global__ __launch_bounds__(256) void gru_mfma(
    const short8* __restrict__ WFp, const short8* __restrict__ WHp,
    const float* __restrict__ bF, const short8* __restrict__ featK,
    const short8* __restrict__ msgK, const short* __restrict__ hidK,
    float* __restrict__ outp)
{
  __shared__ __align__(16) char smem[49152];
  __shared__ float sBias[192];
  short8* sW = (short8*)smem;
  float* sOut = (float*)smem;
  const int tid = threadIdx.x;
  for (int idx = tid; idx < 1536; idx += 256) {
    sW[idx] = WFp[idx];
    sW[1536 + idx] = WHp[idx];
  }
  if (tid < 192) sBias[tid] = bF[tid];
  __syncthreads();

  const int lane = tid & 63, w = tid >> 6;
  const int q = lane >> 4, lj = lane & 15;
  const int j0 = blockIdx.x * 64;
  const int n = blockIdx.y;
  const int j = j0 + w * 16 + lj;
  const short8* Fn = featK + (long)n * 8 * TV;
  const short8* Mn = msgK + (long)n * 8 * TV;

  f32x4 accF[12], accH[12];
  for (int a = 0; a < 12; ++a) {
    accF[a] = (f32x4){0.f, 0.f, 0.f, 0.f};
    accH[a] = (f32x4){0.f, 0.f, 0.f, 0.f};
  }
  for (int c = 0; c < 2; ++c) {
    short8 bFf = Fn[(long)(c * 4 + q) * TV + j];
    short8 bHf = Mn[(long)(c * 4 + q) * TV + j];
#pragma unroll
    for (int mf = 0; mf < 12; ++mf) {
      short8 af = sW[(mf * 2 + c) * 64 + lane];
      accF[mf] = __builtin_amdgcn_mfma_f32_16x16x32_bf16(af, bFf, accF[mf], 0, 0, 0);
      short8 ah = sW[1536 + (mf * 2 + c) * 64 + lane];
      accH[mf] = __builtin_amdgcn_mfma_f32_16x16x32_bf16(ah, bHf, accH[mf], 0, 0, 0);
    }
  }
  __syncthreads();  // all waves done reading weights before aliasing

  const short* Hn = hidK + (long)n * 64 * TV;
#pragma unroll
  for (int mf = 0; mf < 4; ++mf) {
    int k0 = mf * 16 + q * 4;
    int g = k0 >> 3, i0 = k0 & 7;
    short4v h4 = *(const short4v*)&Hn[((long)g * TV + j) * 8 + i0];
#pragma unroll
    for (int r = 0; r < 4; ++r) {
      int o = k0 + r;
      float rp = accF[mf][r] + sBias[o] + accH[mf][r];
      float zp = accF[mf + 4][r] + sBias[64 + o] + accH[mf + 4][r];
      float np = accF[mf + 8][r] + sBias[128 + o];
      float rv = 1.f / (1.f + __expf(-rp));
      float zv = 1.f / (1.f + __expf(-zp));
      float nn = tanhf(np + rv * accH[mf + 8][r]);
      float hv = b2f(h4[r]);
      sOut[o * 68 + (w * 16 + lj)] = (1.f - zv) * nn + zv * hv;
    }
  }
  __syncthreads();
  float* On = outp + (long)n * 64 * TV;
  for (int u2 = tid; u2 < 1024; u2 += 256) {
    int row = u2 >> 4, c4 = u2 & 15;
    float4 vv = *(const float4*)&sOut[row * 68 + c4 * 4];
    *(float4*)&On[(long)row * TV + j0 + c4 * 4] = vv;
  }
}

// ===========================================================================
extern "C" void kernel_launch(void* const* d_in, const int* in_sizes, int n_in,
                              void* d_out, int out_size, void* d_ws, size_t ws_size,
                              hipStream_t stream)
{
  const float* feature = (const float*)d_in[0];
  const float* hidden  = (const float*)d_in[1];
  const float* Amat    = (const float*)d_in[2];
  const float* PAmat   = (const float*)d_in[3];
  const float* caw = (const float*)d_in[4];
  const float* cab = (const float*)d_in[5];
  const float* cbw = (const float*)d_in[6];
  const float* cbb = (const float*)d_in[7];
  const float* cdw = (const float*)d_in[8];
  const float* cdb = (const float*)d_in[9];
  const float* gbn_g = (const float*)d_in[10];
  const float* gbn_b = (const float*)d_in[11];
  const float* gbn_m = (const float*)d_in[12];
  const float* gbn_v = (const float*)d_in[13];
  const float* tcn_w = (const float*)d_in[14];
  const float* tcn_b = (const float*)d_in[15];
  const float* tbn_g = (const float*)d_in[16];
  const float* tbn_b = (const float*)d_in[17];
  const float* tbn_m = (const float*)d_in[18];
  const float* tbn_v = (const float*)d_in[19];
  const float* W_ir = (const float*)d_in[20];
  const float* W_ii = (const float*)d_in[21];
  const float* W_in = (const float*)d_in[22];
  const float* W_hr = (const float*)d_in[23];
  const float* W_hi = (const float*)d_in[24];
  const float* W_hh = (const float*)d_in[25];
  const float* b_ir = (const float*)d_in[26];
  const float* b_ii = (const float*)d_in[27];
  const float* b_in = (const float*)d_in[28];
  float* out = (float*)d_out;

  // n-chunk sizing: bf16 buffers 544 rows-equivalent * TV * 2B per n
  int Nc = NTOT;
  while (Nc > 1) {
    size_t need = (size_t)1088 * TV * Nc + (size_t)Nc * 30000 * 4 +
                  (size_t)Nc * 1875 * 4 + 79872 * 2 + 288 * 4 + 4096;
    if (need <= ws_size) break;
    Nc >>= 1;
  }

  char* p = (char*)d_ws;
  short* hidK = (short*)p;  p += (size_t)Nc * 64 * TV * 2;
  short* featK = (short*)p; p += (size_t)Nc * 64 * TV * 2;
  short* abK = (short*)p;   p += (size_t)Nc * 96 * TV * 2;
  short* uB = (short*)p;    p += (size_t)Nc * 192 * TV * 2;
  short* gcnK = (short*)p;  p += (size_t)Nc * 64 * TV * 2;
  short* msgK = (short*)p;  p += (size_t)Nc * 64 * TV * 2;
  float* partial = (float*)p; p += (size_t)Nc * 30000 * 4;
  float* att = (float*)p;     p += (size_t)Nc * 1875 * 4;
  p = (char*)(((size_t)p + 15) & ~(size_t)15);
  short* P = (short*)p;       p += 79872 * 2;
  float* Pb = (float*)p;

  pack_kernel<<<dim3(41), dim3(256), 0, stream>>>(
      tcn_w, caw, cbw, cdw, W_ir, W_ii, W_in, W_hr, W_hi, W_hh,
      cab, cbb, b_ir, b_ii, b_in, P, Pb);

  const long s64 = (long)64 * TV;
  for (int c0 = 0; c0 < NTOT; c0 += Nc) {
    const float* hidc = hidden + (long)c0 * s64;
    const float* featc = feature + (long)c0 * s64;
    float* outc = out + (long)c0 * s64;

    convert_kernel<<<dim3(25, 16, Nc), 256, 0, stream>>>(hidc, featc, hidK, featK);
    // ab = (caw|cbw) @ hid  -> KJ8
    gemm_mfma<<<dim3(50, 2, Nc), 256, 0, stream>>>(
        (const short8*)P, (const short8*)hidK, abK, Pb, 96, 1,
        (long)8 * TV, (long)96 * TV);
    att_partial<<<dim3(16, 3, Nc), 256, 0, stream>>>(abK, partial);
    att_reduce<<<dim3(3, Nc), 256, 0, stream>>>(partial, Amat, PAmat, att);
    // u = cdw @ hid -> row-major bf16
    gemm_mfma<<<dim3(50, 3, Nc), 256, 0, stream>>>(
        (const short8*)P + 768, (const short8*)hidK, uB, nullptr, 192, 0,
        (long)8 * TV, (long)192 * TV);
    att_apply<<<dim3(8, 8, Nc), 256, 0, stream>>>(
        uB, att, hidK, cdb, gbn_g, gbn_b, gbn_m, gbn_v, gcnK);
    tcn_mfma<<<dim3(50, Nc), 256, 0, stream>>>(
        (const short8*)P + 5376, (const short8*)gcnK, hidK, tcn_b,
        tbn_g, tbn_b, tbn_m, tbn_v, msgK);
    gru_mfma<<<dim3(100, Nc), 256, 0, stream>>>(
        (const short8*)P + 2304, (const short8*)P + 3840, Pb + 96,
        (const short8*)featK, (const short8*)msgK, hidK, outc);
  }
}

// Round 4
// 366.576 us; speedup vs baseline: 5.2279x; 1.2455x over previous
//
#include <hip/hip_runtime.h>
#include <math.h>

#define TV 6400
#define NTOT 32

typedef __attribute__((ext_vector_type(8))) short short8;
typedef __attribute__((ext_vector_type(4))) short short4v;
typedef __attribute__((ext_vector_type(4))) float f32x4;

__device__ __forceinline__ float b2f(short s) {
  unsigned u = ((unsigned)(unsigned short)s) << 16;
  return __uint_as_float(u);
}
__device__ __forceinline__ short f2b(float f) {
  unsigned u = __float_as_uint(f);
  u = (u + 0x7FFF + ((u >> 16) & 1)) >> 16;
  return (short)u;
}

// ===========================================================================
// Pack weights to bf16 frag-major (unit = 64 lanes x 8 bf16 = one a-frag).
// Units: Wab[0,768) Wu[768,2304) WF[2304,3840) WH[3840,5376) wT[5376,9984).
// Biases fp32 in Pb: bab[0,96) bF[96,288).
// ===========================================================================
__global__ __launch_bounds__(256) void pack_kernel(
    const float* __restrict__ tcn_w, const float* __restrict__ caw,
    const float* __restrict__ cbw, const float* __restrict__ cdw,
    const float* __restrict__ W_ir, const float* __restrict__ W_ii,
    const float* __restrict__ W_in, const float* __restrict__ W_hr,
    const float* __restrict__ W_hi, const float* __restrict__ W_hh,
    const float* __restrict__ cab, const float* __restrict__ cbb,
    const float* __restrict__ b_ir, const float* __restrict__ b_ii,
    const float* __restrict__ b_in,
    short* __restrict__ P, float* __restrict__ Pb)
{
  int idx = blockIdx.x * 256 + threadIdx.x;
  if (idx < 9984) {
    int lane = idx & 63;
    int rest = idx >> 6;
    int c = rest & 1;
    rest >>= 1;
    int mloc = lane & 15, kb = c * 32 + (lane >> 4) * 8;
    short8 v;
    if (rest < 6) {            // Wab
      int m = rest * 16 + mloc;
      for (int i = 0; i < 8; ++i)
        v[i] = f2b(m < 48 ? caw[m * 64 + kb + i] : cbw[(m - 48) * 64 + kb + i]);
    } else if (rest < 18) {    // Wu = cdw [192][64]
      int m = (rest - 6) * 16 + mloc;
      for (int i = 0; i < 8; ++i) v[i] = f2b(cdw[m * 64 + kb + i]);
    } else if (rest < 30) {    // WF
      int m = (rest - 18) * 16 + mloc;
      const float* W = (m < 64) ? W_ir : (m < 128 ? W_ii : W_in);
      int mr = m & 63;
      for (int i = 0; i < 8; ++i) v[i] = f2b(W[mr * 64 + kb + i]);
    } else if (rest < 42) {    // WH
      int m = (rest - 30) * 16 + mloc;
      const float* W = (m < 64) ? W_hr : (m < 128 ? W_hi : W_hh);
      int mr = m & 63;
      for (int i = 0; i < 8; ++i) v[i] = f2b(W[mr * 64 + kb + i]);
    } else {                   // wT: tcn_w [o][c][kk]
      int t = rest - 42;
      int kk = t >> 2, mf = t & 3;
      int o = mf * 16 + mloc;
      for (int i = 0; i < 8; ++i) v[i] = f2b(tcn_w[o * 576 + (kb + i) * 9 + kk]);
    }
    *(short8*)(P + (size_t)idx * 8) = v;
  } else if (idx < 9984 + 288) {
    int r = idx - 9984;
    if (r < 96) Pb[r] = (r < 48) ? cab[r] : cbb[r - 48];
    else {
      int q = r - 96;
      Pb[r] = (q < 64) ? b_ir[q] : (q < 128 ? b_ii[q - 64] : b_in[q - 128]);
    }
  }
}

// ===========================================================================
// fp32 [64][TV] -> KJ8 bf16 [8][TV][8] for hidden and feature
// ===========================================================================
__global__ __launch_bounds__(256) void convert_kernel(
    const float* __restrict__ hid, const float* __restrict__ feat,
    short* __restrict__ hidK, short* __restrict__ featK)
{
  int j = blockIdx.x * 256 + threadIdx.x;
  int gy = blockIdx.y;
  int n = blockIdx.z;
  const float* src = ((gy < 8) ? hid : feat) + ((long)n * 64 + (long)(gy & 7) * 8) * TV + j;
  short* dst = ((gy < 8) ? hidK : featK) + (((long)n * 8 + (gy & 7)) * TV + j) * 8;
  short8 o;
#pragma unroll
  for (int i = 0; i < 8; ++i) o[i] = f2b(src[(long)i * TV]);
  *(short8*)dst = o;
}

// ===========================================================================
// ab = (caw|cbw) @ hid, M=96 in ONE m-pass (hidK read once) -> abK (KJ8)
// ===========================================================================
__global__ __launch_bounds__(256) void ab_gemm(
    const short8* __restrict__ Wp, const short8* __restrict__ Bk,
    short* __restrict__ Cout, const float* __restrict__ bias)
{
  const int tid = threadIdx.x;
  const int lane = tid & 63, w = tid >> 6;
  const int q = lane >> 4, lj = lane & 15;
  const int j0 = blockIdx.x * 128;
  const int n = blockIdx.y;
  const short8* Bn = Bk + (long)n * 8 * TV;
  short* Cn = Cout + (long)n * 96 * TV;

  f32x4 acc[6][2];
  for (int a = 0; a < 6; ++a) for (int b = 0; b < 2; ++b)
    acc[a][b] = (f32x4){0.f, 0.f, 0.f, 0.f};

  for (int c = 0; c < 2; ++c) {
    short8 bf0 = Bn[(long)(c * 4 + q) * TV + j0 + (w * 2 + 0) * 16 + lj];
    short8 bf1 = Bn[(long)(c * 4 + q) * TV + j0 + (w * 2 + 1) * 16 + lj];
#pragma unroll
    for (int mf = 0; mf < 6; ++mf) {
      short8 af = Wp[(mf * 2 + c) * 64 + lane];
      acc[mf][0] = __builtin_amdgcn_mfma_f32_16x16x32_bf16(af, bf0, acc[mf][0], 0, 0, 0);
      acc[mf][1] = __builtin_amdgcn_mfma_f32_16x16x32_bf16(af, bf1, acc[mf][1], 0, 0, 0);
    }
  }
#pragma unroll
  for (int mf = 0; mf < 6; ++mf) {
    int k0 = mf * 16 + q * 4;
    int g = k0 >> 3, i0 = k0 & 7;
    float bv[4];
#pragma unroll
    for (int r = 0; r < 4; ++r) bv[r] = bias[k0 + r];
#pragma unroll
    for (int jf = 0; jf < 2; ++jf) {
      int j = j0 + (w * 2 + jf) * 16 + lj;
      short4v o4;
#pragma unroll
      for (int r = 0; r < 4; ++r) o4[r] = f2b(acc[mf][jf][r] + bv[r]);
      *(short4v*)(Cn + ((long)g * TV + j) * 8 + i0) = o4;
    }
  }
}

// ===========================================================================
// Attention split-K partial from abK (KJ8 bf16)
// ===========================================================================
__global__ __launch_bounds__(256) void att_partial(
    const short* __restrict__ abK, float* __restrict__ partial)
{
  const int ch = blockIdx.x, i = blockIdx.y, n = blockIdx.z;
  __shared__ float sA[6400], sB[6400];
  const int tid = threadIdx.x;
  const long nb = (long)n * 96 * TV;
  const int t0 = ch * 16;
  for (int idx = tid; idx < 800; idx += 256) {
    int gh = idx / 400, jl = idx - gh * 400;
    long j = (long)t0 * 25 + jl;
    short8 va = *(const short8*)&abK[nb + ((long)(2 * i + gh) * TV + j) * 8];
    short8 vb = *(const short8*)&abK[nb + ((long)(6 + 2 * i + gh) * TV + j) * 8];
#pragma unroll
    for (int e = 0; e < 8; ++e) {
      sA[(gh * 8 + e) * 400 + jl] = b2f(va[e]);
      sB[(gh * 8 + e) * 400 + jl] = b2f(vb[e]);
    }
  }
  __syncthreads();
  const int a0 = tid >> 4, b0 = tid & 15;
  const int v1 = a0 + 16, w1 = b0 + 16;
  const int v1c = (v1 < 25) ? v1 : 0, w1c = (w1 < 25) ? w1 : 0;
  float acc00 = 0, acc01 = 0, acc10 = 0, acc11 = 0;
#pragma unroll 8
  for (int r = 0; r < 256; ++r) {
    float av0 = sA[r * 25 + a0], av1 = sA[r * 25 + v1c];
    float bw0 = sB[r * 25 + b0], bw1 = sB[r * 25 + w1c];
    acc00 += av0 * bw0; acc01 += av0 * bw1;
    acc10 += av1 * bw0; acc11 += av1 * bw1;
  }
  const float scale = 1.0f / 4096.0f;
  float* pp = partial + (((long)(n * 3 + i) * 16) + ch) * 625;
  pp[a0 * 25 + b0] = acc00 * scale;
  if (w1 < 25) pp[a0 * 25 + w1] = acc01 * scale;
  if (v1 < 25) pp[v1 * 25 + b0] = acc10 * scale;
  if (v1 < 25 && w1 < 25) pp[v1 * 25 + w1] = acc11 * scale;
}

// ===========================================================================
// Reduce partials, column softmax, +A+PA -> attP in bf16 A-frag layout:
// attP[((n*3+i)*2+wf)*64+lane] unit: A[m=w=wf*16+(lane&15)][k=v=(lane>>4)*8+e]
// ===========================================================================
__global__ __launch_bounds__(256) void att_reduce(
    const float* __restrict__ partial, const float* __restrict__ Amat,
    const float* __restrict__ PAmat, short* __restrict__ attP)
{
  const int i = blockIdx.x, n = blockIdx.y;
  __shared__ float sL[625];
  const int tid = threadIdx.x;
  const float* pp = partial + ((long)(n * 3 + i) * 16) * 625;
  for (int idx = tid; idx < 625; idx += 256) {
    float s = 0.f;
#pragma unroll
    for (int c = 0; c < 16; ++c) s += pp[c * 625 + idx];
    sL[idx] = s;
  }
  __syncthreads();
  if (tid < 25) {
    const int w = tid;
    float mx = -1e30f;
#pragma unroll
    for (int v = 0; v < 25; ++v) mx = fmaxf(mx, sL[v * 25 + w]);
    float e[25];
    float s = 0.f;
#pragma unroll
    for (int v = 0; v < 25; ++v) { e[v] = __expf(sL[v * 25 + w] - mx); s += e[v]; }
    float inv = 1.f / s;
#pragma unroll
    for (int v = 0; v < 25; ++v)
      sL[v * 25 + w] = e[v] * inv + Amat[i * 625 + v * 25 + w] + PAmat[i * 625 + v * 25 + w];
  }
  __syncthreads();
  if (tid < 128) {
    int wf = tid >> 6, lane = tid & 63;
    int q = lane >> 4, lj = lane & 15;
    int w = wf * 16 + lj;
    short8 o = {0, 0, 0, 0, 0, 0, 0, 0};
    if (w < 25) {
#pragma unroll
      for (int e2 = 0; e2 < 8; ++e2) {
        int v = q * 8 + e2;
        if (v < 25) o[e2] = f2b(sL[v * 25 + w]);
      }
    }
    *(short8*)(attP + (size_t)(((long)(n * 3 + i) * 2 + wf) * 64 + lane) * 8) = o;
  }
}

// ===========================================================================
// FUSED: u = cdw@hid (MFMA, staged in LDS bf16) then y = sum_i u_i x att_i
// (MFMA, A=att^T frags, B gathered from LDS), epilogue gBN+residual+relu.
// Block = (tt of 4 t's = 100 cols, n); 4 waves, wave w owns t_local=w.
// ===========================================================================
#define UST 114  // u-tile LDS row stride (shorts)
#define OST 101  // sOut LDS row stride (shorts, bf16)
__global__ __launch_bounds__(256) void gcn_fused(
    const short8* __restrict__ Wu, const short8* __restrict__ attP,
    const short8* __restrict__ hidK, const float* __restrict__ cdb,
    const float* __restrict__ gg, const float* __restrict__ gb,
    const float* __restrict__ gm, const float* __restrict__ gv,
    short* __restrict__ gcnK)
{
  __shared__ short uT[192 * UST];
  __shared__ short sOut[64 * OST];
  __shared__ float A2[64], B2[64];
  const int tid = threadIdx.x;
  if (tid < 64) {
    float sc = gg[tid] * rsqrtf(gv[tid] + 1e-5f);
    A2[tid] = sc;
    float bias = cdb[tid] + cdb[64 + tid] + cdb[128 + tid];
    B2[tid] = bias * sc + (gb[tid] - gm[tid] * sc);
  }
  const int lane = tid & 63, w = tid >> 6;
  const int q = lane >> 4, lj = lane & 15;
  const int tt = blockIdx.x, n = blockIdx.y;
  const int jb = tt * 100;
  const short8* Hn = hidK + (long)n * 8 * TV;

  // ---- phase 1: u-tile [192][100] via MFMA; wave w does mf = 3w..3w+2
  f32x4 uacc[3][7];
  for (int a = 0; a < 3; ++a) for (int b = 0; b < 7; ++b)
    uacc[a][b] = (f32x4){0.f, 0.f, 0.f, 0.f};
  for (int c = 0; c < 2; ++c) {
    short8 bf[7];
#pragma unroll
    for (int jf = 0; jf < 7; ++jf)
      bf[jf] = Hn[(long)(c * 4 + q) * TV + jb + jf * 16 + lj];
#pragma unroll
    for (int ml = 0; ml < 3; ++ml) {
      short8 af = Wu[((w * 3 + ml) * 2 + c) * 64 + lane];
#pragma unroll
      for (int jf = 0; jf < 7; ++jf)
        uacc[ml][jf] = __builtin_amdgcn_mfma_f32_16x16x32_bf16(af, bf[jf], uacc[ml][jf], 0, 0, 0);
    }
  }
#pragma unroll
  for (int ml = 0; ml < 3; ++ml) {
    int row0 = (w * 3 + ml) * 16 + q * 4;
#pragma unroll
    for (int jf = 0; jf < 7; ++jf) {
      int col = jf * 16 + lj;
#pragma unroll
      for (int r = 0; r < 4; ++r)
        uT[(row0 + r) * UST + col] = f2b(uacc[ml][jf][r]);
    }
  }
  __syncthreads();

  // ---- phase 2: mixing for t_local = w; A = attP, B gathered from uT
  const int colt = w * 25;
  short8 attA[6];
#pragma unroll
  for (int i = 0; i < 3; ++i)
#pragma unroll
    for (int wf = 0; wf < 2; ++wf)
      attA[i * 2 + wf] = attP[((long)(n * 3 + i) * 2 + wf) * 64 + lane];

  f32x4 macc[2][4];
  for (int a = 0; a < 2; ++a) for (int b = 0; b < 4; ++b)
    macc[a][b] = (f32x4){0.f, 0.f, 0.f, 0.f};
#pragma unroll
  for (int i = 0; i < 3; ++i) {
#pragma unroll
    for (int of = 0; of < 4; ++of) {
      int row = i * 64 + of * 16 + lj;
      short8 bf;
#pragma unroll
      for (int e = 0; e < 8; ++e)
        bf[e] = uT[row * UST + colt + q * 8 + e];
      macc[0][of] = __builtin_amdgcn_mfma_f32_16x16x32_bf16(attA[i * 2 + 0], bf, macc[0][of], 0, 0, 0);
      macc[1][of] = __builtin_amdgcn_mfma_f32_16x16x32_bf16(attA[i * 2 + 1], bf, macc[1][of], 0, 0, 0);
    }
  }
#pragma unroll
  for (int wf = 0; wf < 2; ++wf)
#pragma unroll
    for (int of = 0; of < 4; ++of)
#pragma unroll
      for (int r = 0; r < 4; ++r) {
        int wl = wf * 16 + q * 4 + r;
        if (wl < 25)
          sOut[(of * 16 + lj) * OST + colt + wl] = f2b(macc[wf][of][r]);
      }
  __syncthreads();

  // ---- epilogue: 800 units (og 0..7, col 0..99), coalesced KJ8 in/out
  const short* HnS = (const short*)Hn;
  short* Gn = gcnK + (long)n * 64 * TV;
  for (int u2 = tid; u2 < 800; u2 += 256) {
    int col = u2 % 100, og = u2 / 100;
    long ubase = ((long)og * TV + jb + col) * 8;
    short8 h8 = *(const short8*)&HnS[ubase];
    short8 o8;
#pragma unroll
    for (int e = 0; e < 8; ++e) {
      int o = og * 8 + e;
      float acc = b2f(sOut[o * OST + col]);
      float vv = fmaxf(acc * A2[o] + B2[o] + b2f(h8[e]), 0.f);
      o8[e] = f2b(vv);
    }
    *(short8*)&Gn[ubase] = o8;
  }
}

// ===========================================================================
// TCN: 9 column-shifted K=64 MFMA accumulations + tBN + residual relu
// ===========================================================================
__global__ __launch_bounds__(256) void tcn_mfma(
    const short8* __restrict__ wTp, const short8* __restrict__ gcnK,
    const short* __restrict__ hidK, const float* __restrict__ tcn_b,
    const float* __restrict__ pbg, const float* __restrict__ pbb,
    const float* __restrict__ pbm, const float* __restrict__ pbv,
    short* __restrict__ msgK)
{
  __shared__ float A2[64], B2[64];
  const int tid = threadIdx.x;
  if (tid < 64) {
    float sc = pbg[tid] * rsqrtf(pbv[tid] + 1e-5f);
    A2[tid] = sc;
    B2[tid] = tcn_b[tid] * sc + (pbb[tid] - pbm[tid] * sc);
  }
  __syncthreads();
  const int lane = tid & 63, w = tid >> 6;
  const int q = lane >> 4, lj = lane & 15;
  const int j0 = blockIdx.x * 128;
  const int n = blockIdx.y;
  const short8* Bn = gcnK + (long)n * 8 * TV;
  const short8 zero8 = {0, 0, 0, 0, 0, 0, 0, 0};

  f32x4 acc[4][2];
  for (int a = 0; a < 4; ++a) for (int b = 0; b < 2; ++b)
    acc[a][b] = (f32x4){0.f, 0.f, 0.f, 0.f};

  for (int kk = 0; kk < 9; ++kk) {
    const int shift = (kk - 4) * 25;
    for (int c = 0; c < 2; ++c) {
      short8 bfv[2];
#pragma unroll
      for (int jf = 0; jf < 2; ++jf) {
        int col = j0 + (w * 2 + jf) * 16 + lj + shift;
        bool valid = ((unsigned)col < (unsigned)TV);
        short8 t = Bn[(long)(c * 4 + q) * TV + (valid ? col : 0)];
        bfv[jf] = valid ? t : zero8;
      }
#pragma unroll
      for (int mf = 0; mf < 4; ++mf) {
        short8 af = wTp[((kk * 4 + mf) * 2 + c) * 64 + lane];
        acc[mf][0] = __builtin_amdgcn_mfma_f32_16x16x32_bf16(af, bfv[0], acc[mf][0], 0, 0, 0);
        acc[mf][1] = __builtin_amdgcn_mfma_f32_16x16x32_bf16(af, bfv[1], acc[mf][1], 0, 0, 0);
      }
    }
  }

  short* Mn = msgK + (long)n * 64 * TV;
  const short* Hn = hidK + (long)n * 64 * TV;
#pragma unroll
  for (int mf = 0; mf < 4; ++mf) {
    int k0 = mf * 16 + q * 4;
    int g = k0 >> 3, i0 = k0 & 7;
#pragma unroll
    for (int jf = 0; jf < 2; ++jf) {
      int j = j0 + (w * 2 + jf) * 16 + lj;
      long base = ((long)g * TV + j) * 8 + i0;
      short4v h4 = *(const short4v*)&Hn[base];
      short4v o4;
#pragma unroll
      for (int r = 0; r < 4; ++r) {
        float v = acc[mf][jf][r] * A2[k0 + r] + B2[k0 + r] + b2f(h4[r]);
        o4[r] = f2b(fmaxf(v, 0.f));
      }
      *(short4v*)&Mn[base] = o4;
    }
  }
}

// ===========================================================================
// Fused GRU: F = WF@featK, H = WH@msgK, gates, out fp32
// ===========================================================================
__global__ __launch_bounds__(256) void gru_mfma(
    const short8* __restrict__ WFp, const short8* __restrict__ WHp,
    const float* __restrict__ bF, const short8* __restrict__ featK,
    const short8* __restrict__ msgK, const short* __restrict__ hidK,
    float* __restrict__ outp)
{
  __shared__ __align__(16) char smem[49152];
  __shared__ float sBias[192];
  short8* sW = (short8*)smem;
  float* sOut = (float*)smem;
  const int tid = threadIdx.x;
  for (int idx = tid; idx < 1536; idx += 256) {
    sW[idx] = WFp[idx];
    sW[1536 + idx] = WHp[idx];
  }
  if (tid < 192) sBias[tid] = bF[tid];
  __syncthreads();

  const int lane = tid & 63, w = tid >> 6;
  const int q = lane >> 4, lj = lane & 15;
  const int j0 = blockIdx.x * 64;
  const int n = blockIdx.y;
  const int j = j0 + w * 16 + lj;
  const short8* Fn = featK + (long)n * 8 * TV;
  const short8* Mn = msgK + (long)n * 8 * TV;

  f32x4 accF[12], accH[12];
  for (int a = 0; a < 12; ++a) {
    accF[a] = (f32x4){0.f, 0.f, 0.f, 0.f};
    accH[a] = (f32x4){0.f, 0.f, 0.f, 0.f};
  }
  for (int c = 0; c < 2; ++c) {
    short8 bFf = Fn[(long)(c * 4 + q) * TV + j];
    short8 bHf = Mn[(long)(c * 4 + q) * TV + j];
#pragma unroll
    for (int mf = 0; mf < 12; ++mf) {
      short8 af = sW[(mf * 2 + c) * 64 + lane];
      accF[mf] = __builtin_amdgcn_mfma_f32_16x16x32_bf16(af, bFf, accF[mf], 0, 0, 0);
      short8 ah = sW[1536 + (mf * 2 + c) * 64 + lane];
      accH[mf] = __builtin_amdgcn_mfma_f32_16x16x32_bf16(ah, bHf, accH[mf], 0, 0, 0);
    }
  }
  __syncthreads();

  const short* Hn = hidK + (long)n * 64 * TV;
#pragma unroll
  for (int mf = 0; mf < 4; ++mf) {
    int k0 = mf * 16 + q * 4;
    int g = k0 >> 3, i0 = k0 & 7;
    short4v h4 = *(const short4v*)&Hn[((long)g * TV + j) * 8 + i0];
#pragma unroll
    for (int r = 0; r < 4; ++r) {
      int o = k0 + r;
      float rp = accF[mf][r] + sBias[o] + accH[mf][r];
      float zp = accF[mf + 4][r] + sBias[64 + o] + accH[mf + 4][r];
      float np = accF[mf + 8][r] + sBias[128 + o];
      float rv = 1.f / (1.f + __expf(-rp));
      float zv = 1.f / (1.f + __expf(-zp));
      float nn = tanhf(np + rv * accH[mf + 8][r]);
      float hv = b2f(h4[r]);
      sOut[o * 68 + (w * 16 + lj)] = (1.f - zv) * nn + zv * hv;
    }
  }
  __syncthreads();
  float* On = outp + (long)n * 64 * TV;
  for (int u2 = tid; u2 < 1024; u2 += 256) {
    int row = u2 >> 4, c4 = u2 & 15;
    float4 vv = *(const float4*)&sOut[row * 68 + c4 * 4];
    *(float4*)&On[(long)row * TV + j0 + c4 * 4] = vv;
  }
}

// ===========================================================================
extern "C" void kernel_launch(void* const* d_in, const int* in_sizes, int n_in,
                              void* d_out, int out_size, void* d_ws, size_t ws_size,
                              hipStream_t stream)
{
  const float* feature = (const float*)d_in[0];
  const float* hidden  = (const float*)d_in[1];
  const float* Amat    = (const float*)d_in[2];
  const float* PAmat   = (const float*)d_in[3];
  const float* caw = (const float*)d_in[4];
  const float* cab = (const float*)d_in[5];
  const float* cbw = (const float*)d_in[6];
  const float* cbb = (const float*)d_in[7];
  const float* cdw = (const float*)d_in[8];
  const float* cdb = (const float*)d_in[9];
  const float* gbn_g = (const float*)d_in[10];
  const float* gbn_b = (const float*)d_in[11];
  const float* gbn_m = (const float*)d_in[12];
  const float* gbn_v = (const float*)d_in[13];
  const float* tcn_w = (const float*)d_in[14];
  const float* tcn_b = (const float*)d_in[15];
  const float* tbn_g = (const float*)d_in[16];
  const float* tbn_b = (const float*)d_in[17];
  const float* tbn_m = (const float*)d_in[18];
  const float* tbn_v = (const float*)d_in[19];
  const float* W_ir = (const float*)d_in[20];
  const float* W_ii = (const float*)d_in[21];
  const float* W_in = (const float*)d_in[22];
  const float* W_hr = (const float*)d_in[23];
  const float* W_hi = (const float*)d_in[24];
  const float* W_hh = (const float*)d_in[25];
  const float* b_ir = (const float*)d_in[26];
  const float* b_ii = (const float*)d_in[27];
  const float* b_in = (const float*)d_in[28];
  float* out = (float*)d_out;

  // n-chunk sizing (layout depends only on ws_size)
  int Nc = NTOT;
  while (Nc > 1) {
    size_t need = (size_t)352 * TV * 2 * Nc + (size_t)Nc * 30000 * 4 +
                  (size_t)Nc * 3072 * 2 + 79872 * 2 + 288 * 4 + 4096;
    if (need <= ws_size) break;
    Nc >>= 1;
  }

  char* p = (char*)d_ws;
  short* hidK = (short*)p;  p += (size_t)Nc * 64 * TV * 2;
  short* featK = (short*)p; p += (size_t)Nc * 64 * TV * 2;
  short* abK = (short*)p;   p += (size_t)Nc * 96 * TV * 2;
  short* gcnK = (short*)p;  p += (size_t)Nc * 64 * TV * 2;
  short* msgK = (short*)p;  p += (size_t)Nc * 64 * TV * 2;
  float* partial = (float*)p; p += (size_t)Nc * 30000 * 4;
  short* attP = (short*)p;    p += (size_t)Nc * 3072 * 2;
  p = (char*)(((size_t)p + 15) & ~(size_t)15);
  short* P = (short*)p;       p += 79872 * 2;
  float* Pb = (float*)p;

  pack_kernel<<<dim3(41), dim3(256), 0, stream>>>(
      tcn_w, caw, cbw, cdw, W_ir, W_ii, W_in, W_hr, W_hi, W_hh,
      cab, cbb, b_ir, b_ii, b_in, P, Pb);

  const long s64 = (long)64 * TV;
  for (int c0 = 0; c0 < NTOT; c0 += Nc) {
    const float* hidc = hidden + (long)c0 * s64;
    const float* featc = feature + (long)c0 * s64;
    float* outc = out + (long)c0 * s64;

    convert_kernel<<<dim3(25, 16, Nc), 256, 0, stream>>>(hidc, featc, hidK, featK);
    ab_gemm<<<dim3(50, Nc), 256, 0, stream>>>(
        (const short8*)P, (const short8*)hidK, abK, Pb);
    att_partial<<<dim3(16, 3, Nc), 256, 0, stream>>>(abK, partial);
    att_reduce<<<dim3(3, Nc), 256, 0, stream>>>(partial, Amat, PAmat, attP);
    gcn_fused<<<dim3(64, Nc), 256, 0, stream>>>(
        (const short8*)P + 768, (const short8*)attP, (const short8*)hidK,
        cdb, gbn_g, gbn_b, gbn_m, gbn_v, gcnK);
    tcn_mfma<<<dim3(50, Nc), 256, 0, stream>>>(
        (const short8*)P + 5376, (const short8*)gcnK, hidK, tcn_b,
        tbn_g, tbn_b, tbn_m, tbn_v, msgK);
    gru_mfma<<<dim3(100, Nc), 256, 0, stream>>>(
        (const short8*)P + 2304, (const short8*)P + 3840, Pb + 96,
        (const short8*)featK, (const short8*)msgK, hidK, outc);
  }
}